// Round 6
// baseline (1979.902 us; speedup 1.0000x reference)
//
#include <hip/hip_runtime.h>

// DGP-RF embeddings, fused MFMA implementation. Round 6.
// R6 thesis (building on R5's confirmed M=64 win, 967->615us):
//  VALU is now the top pipe (53.8%) and LDS (69KB) caps occupancy at 2 blk/CU.
//  Fix both at once: prep-kernel converts X -> Xbf,Xsq (bf16, global, 67MB ea);
//  fused kernel loads A-fragments directly from global (64B/row segments,
//  identical across the WG's 4 waves -> L1-served; base+imm addressing).
//   - kills ALL GEMM1 sq_frag recompute (was ~900 instr/chunk/wave) + staging
//   - LDS = Tm/Tv only (35KB) -> 3 blk/CU via __launch_bounds__(256,3)
//  X now has 8x reuse per WG (unlike R3's single-use stream) and the whole
//  working set (201MB X + 1.8MB weights) is L3-resident.
//  Fallback to the R5 kernel if ws_size can't hold the X arrays.

#define NPTS   131072
#define SGRP   16384
#define DIN    256
#define NRF    1024
#define DOUT   128
#define MT     64            // points per WG
#define NWG    (NPTS / MT)   // 2048

#define XLD    264   // fallback-path X LDS leading dim
#define TLD    136   // 128 + 8 pad

typedef unsigned short ushort_t;
typedef __attribute__((ext_vector_type(8))) short bf16x8;
typedef __attribute__((ext_vector_type(4))) float f32x4;
typedef __attribute__((ext_vector_type(2))) float f32x2;
typedef __attribute__((ext_vector_type(4))) float f32x4v;

__device__ __forceinline__ unsigned short f2bf(float f) {
  unsigned u = __float_as_uint(f);
  u += 0x7fffu + ((u >> 16) & 1u);   // round-to-nearest-even
  return (unsigned short)(u >> 16);
}

__device__ __forceinline__ float fast_rcp(float x) {
#if __has_builtin(__builtin_amdgcn_rcpf)
  return __builtin_amdgcn_rcpf(x);
#else
  return 1.0f / x;
#endif
}
__device__ __forceinline__ float fast_rsq(float x) {
#if __has_builtin(__builtin_amdgcn_rsqf)
  return __builtin_amdgcn_rsqf(x);
#else
  return rsqrtf(x);
#endif
}
__device__ __forceinline__ float fast_exp2(float x) {
#if __has_builtin(__builtin_amdgcn_exp2f)
  return __builtin_amdgcn_exp2f(x);
#else
  return exp2f(x);
#endif
}

// elementwise square of a bf16x8 fragment; pk_mul + round-half-up pack.
__device__ __forceinline__ bf16x8 sq_frag(bf16x8 a) {
  union { bf16x8 h; unsigned u[4]; } in, out;
  in.h = a;
#pragma unroll
  for (int i = 0; i < 4; ++i) {
    unsigned w = in.u[i];
    f32x2 f;
    f[0] = __uint_as_float(w << 16);
    f[1] = __uint_as_float(w & 0xffff0000u);
    f32x2 s = f * f;
    unsigned lo = (__float_as_uint(s[0]) + 0x8000u) >> 16;
    unsigned hi = (__float_as_uint(s[1]) + 0x8000u) & 0xffff0000u;
    out.u[i] = hi | lo;
  }
  return out.h;
}

// Exact Gaussian-ReLU moments (A&S 7.1.26 erf, one shared exp2).
__device__ __forceinline__ void relu_moments(float mu, float v,
                                             float& mo, float& vo) {
  float vpe = v + 1e-8f;
  float rsq = fast_rsq(vpe);
  float s   = vpe * rsq;
  float z   = mu * rsq;
  float E   = fast_exp2(-0.7213475204444817f * z * z);  // exp(-z^2/2)
  float x   = 0.70710678118654752f * fabsf(z);
  float t   = fast_rcp(fmaf(0.3275911f, x, 1.0f));
  float poly = t * fmaf(t, fmaf(t, fmaf(t, fmaf(t, 1.061405429f, -1.453152027f),
                                        1.421413741f), -0.284496736f), 0.254829592f);
  float q   = 0.5f * poly * E;
  float Phi = (z >= 0.0f) ? (1.0f - q) : q;
  float phi = 0.3989422804014327f * E;
  float sphi = s * phi;
  mo = fmaf(mu, Phi, sphi);
  float ey2 = fmaf(fmaf(mu, mu, v), Phi, mu * sphi);
  vo = fmaxf(fmaf(-mo, mo, ey2), 1e-6f);
}

// ---------------- kernel 0: detect whether X_idx is int32 or int64 -------------
__global__ void detect_idx_kernel(const unsigned* __restrict__ raw,
                                  int* __restrict__ flag) {
  __shared__ int any_nz;
  if (threadIdx.x == 0) any_nz = 0;
  __syncthreads();
  if (raw[2 * threadIdx.x + 1] != 0u) atomicOr(&any_nz, 1);
  __syncthreads();
  if (threadIdx.x == 0) *flag = (any_nz == 0) ? 1 : 0;   // 1 => int64
}

// ---------------- kernel 1: convert weights to bf16 ---------------------------
__global__ __launch_bounds__(256) void convert_kernel(
    const float* __restrict__ W1mu, const float* __restrict__ W1var,
    const float* __restrict__ W2mu, const float* __restrict__ W2var,
    ushort_t* __restrict__ w1mu_bf, ushort_t* __restrict__ w1var_bf,
    ushort_t* __restrict__ w2mu_bf, ushort_t* __restrict__ w2b_bf,
    ushort_t* __restrict__ w2var_bf) {
  int i = blockIdx.x * 256 + threadIdx.x;      // grid covers 262144 exactly
  w1mu_bf[i]  = f2bf(W1mu[i]);
  w1var_bf[i] = f2bf(W1var[i]);
  if (i < NRF * DOUT) {
    float m = W2mu[i];
    float v = W2var[i];
    w2mu_bf[i]  = f2bf(m);
    w2b_bf[i]   = f2bf(fmaf(m, m, v));      // W2mu^2 + W2var
    w2var_bf[i] = f2bf(v);
  }
}

// ---------------- kernel 1b: convert X -> bf16 X and bf16 X^2 -----------------
__global__ __launch_bounds__(256) void xprep_kernel(
    const float* __restrict__ X,
    ushort_t* __restrict__ xbf, ushort_t* __restrict__ xsq) {
  size_t i = ((size_t)blockIdx.x * 256 + threadIdx.x) * 4;   // covers N*DIN
  f32x4v x = *(const f32x4v*)(X + i);
  ushort4 b, q;
  b.x = f2bf(x[0]); b.y = f2bf(x[1]); b.z = f2bf(x[2]); b.w = f2bf(x[3]);
  q.x = f2bf(x[0] * x[0]); q.y = f2bf(x[1] * x[1]);
  q.z = f2bf(x[2] * x[2]); q.w = f2bf(x[3] * x[3]);
  *(ushort4*)(xbf + i) = b;
  *(ushort4*)(xsq + i) = q;
}

// ---------------- kernel 2: fused DGP-RF block (global-X path) ----------------
__global__ __launch_bounds__(256, 3) void fused_gx(
    const ushort_t* __restrict__ Xbf, const ushort_t* __restrict__ Xsq,
    const unsigned* __restrict__ Xidx_raw,
    const ushort_t* __restrict__ W1mu, const ushort_t* __restrict__ W1var,
    const ushort_t* __restrict__ W2mu, const ushort_t* __restrict__ W2b,
    const ushort_t* __restrict__ W2var,
    const int* __restrict__ flag64,
    float* __restrict__ acc_means, float* __restrict__ acc_vars) {
  __shared__ ushort_t Tm[MT * TLD];    // 17.4 KB
  __shared__ ushort_t Tv[MT * TLD];    // 17.4 KB
  __shared__ int sidx[MT];

  const int tid = threadIdx.x;
  const int p0  = blockIdx.x * MT;
  const int is64 = *flag64;

  if (tid < MT) {
    int p = p0 + tid;
    sidx[tid] = (int)(is64 ? Xidx_raw[2 * (size_t)p] : Xidx_raw[p]);
  }

  const int lane = tid & 63;
  const int wave = tid >> 6;
  const int l16  = lane & 15;
  const int quad = lane >> 4;
  const int qoff = quad * 8;

  const int nrow0 = (wave * 2 + 0) * 16 + l16;   // B rows this wave owns
  const int nrow1 = (wave * 2 + 1) * 16 + l16;

  // A-fragment base pointers (chunk-invariant; per-load offset k*32 folds to imm)
  const ushort_t* pA[4];
  const ushort_t* pQ[4];
#pragma unroll
  for (int mt = 0; mt < 4; ++mt) {
    size_t ro = (size_t)(p0 + mt * 16 + l16) * DIN + qoff;
    pA[mt] = Xbf + ro;
    pQ[mt] = Xsq + ro;
  }

  f32x4 acc_mo[4][2], acc_vo[4][2];
#pragma unroll
  for (int mt = 0; mt < 4; ++mt)
#pragma unroll
    for (int j = 0; j < 2; ++j) {
      acc_mo[mt][j] = (f32x4){0.f, 0.f, 0.f, 0.f};
      acc_vo[mt][j] = (f32x4){0.f, 0.f, 0.f, 0.f};
    }

  // A double-buffer: preload k=0
  bf16x8 axb[2][4], aqb[2][4];
#pragma unroll
  for (int mt = 0; mt < 4; ++mt) {
    axb[0][mt] = *(const bf16x8*)(pA[mt]);
    aqb[0][mt] = *(const bf16x8*)(pQ[mt]);
  }

  // GEMM1 B double-buffer, preloaded for c=0, k=0,1
  bf16x8 g1mu[2][2], g1vr[2][2];
  {
    const ushort_t* b0 = W1mu + (size_t)nrow0 * DIN + qoff;
    const ushort_t* b1 = W1mu + (size_t)nrow1 * DIN + qoff;
    const ushort_t* v0 = W1var + (size_t)nrow0 * DIN + qoff;
    const ushort_t* v1 = W1var + (size_t)nrow1 * DIN + qoff;
#pragma unroll
    for (int k = 0; k < 2; ++k) {
      g1mu[k][0] = *(const bf16x8*)(b0 + k * 32);
      g1mu[k][1] = *(const bf16x8*)(b1 + k * 32);
      g1vr[k][0] = *(const bf16x8*)(v0 + k * 32);
      g1vr[k][1] = *(const bf16x8*)(v1 + k * 32);
    }
  }

#pragma unroll 1
  for (int c = 0; c < 8; ++c) {
    // per-chunk weight base pointers (k offset folds into load imm)
    const ushort_t* w1m0 = W1mu + ((size_t)(c * 128) + nrow0) * DIN + qoff;
    const ushort_t* w1m1 = W1mu + ((size_t)(c * 128) + nrow1) * DIN + qoff;
    const ushort_t* w1v0 = W1var + ((size_t)(c * 128) + nrow0) * DIN + qoff;
    const ushort_t* w1v1 = W1var + ((size_t)(c * 128) + nrow1) * DIN + qoff;

    f32x4 am[4][2], av[4][2];
#pragma unroll
    for (int mt = 0; mt < 4; ++mt)
#pragma unroll
      for (int nt = 0; nt < 2; ++nt) {
        am[mt][nt] = (f32x4){0.f, 0.f, 0.f, 0.f};
        av[mt][nt] = (f32x4){0.f, 0.f, 0.f, 0.f};
      }

#pragma unroll
    for (int k = 0; k < 8; ++k) {
      const int cur = k & 1, nxt = cur ^ 1;
      bf16x8 cmu0 = g1mu[cur][0], cmu1 = g1mu[cur][1];
      bf16x8 cvr0 = g1vr[cur][0], cvr1 = g1vr[cur][1];
      // refill B slot with k+2 (next chunk's k=0,1 handled at chunk end)
      if (k < 6) {
        g1mu[cur][0] = *(const bf16x8*)(w1m0 + (k + 2) * 32);
        g1mu[cur][1] = *(const bf16x8*)(w1m1 + (k + 2) * 32);
        g1vr[cur][0] = *(const bf16x8*)(w1v0 + (k + 2) * 32);
        g1vr[cur][1] = *(const bf16x8*)(w1v1 + (k + 2) * 32);
      }
      // prefetch A for k+1 (wraps to 0: same data, cache-hot, feeds next chunk)
      const int kn = (k + 1) & 7;
#pragma unroll
      for (int mt = 0; mt < 4; ++mt) {
        axb[nxt][mt] = *(const bf16x8*)(pA[mt] + kn * 32);
        aqb[nxt][mt] = *(const bf16x8*)(pQ[mt] + kn * 32);
      }
#pragma unroll
      for (int mt = 0; mt < 4; ++mt) {
        bf16x8 ax = axb[cur][mt];
        bf16x8 aq = aqb[cur][mt];
        am[mt][0] = __builtin_amdgcn_mfma_f32_16x16x32_bf16(ax, cmu0, am[mt][0], 0, 0, 0);
        am[mt][1] = __builtin_amdgcn_mfma_f32_16x16x32_bf16(ax, cmu1, am[mt][1], 0, 0, 0);
        av[mt][0] = __builtin_amdgcn_mfma_f32_16x16x32_bf16(aq, cvr0, av[mt][0], 0, 0, 0);
        av[mt][1] = __builtin_amdgcn_mfma_f32_16x16x32_bf16(aq, cvr1, av[mt][1], 0, 0, 0);
      }
    }

    // preload next chunk's GEMM1 B (k=0,1): hidden behind moments + GEMM2
    if (c < 7) {
#pragma unroll
      for (int k = 0; k < 2; ++k) {
        g1mu[k][0] = *(const bf16x8*)(w1m0 + 128 * DIN + k * 32);
        g1mu[k][1] = *(const bf16x8*)(w1m1 + 128 * DIN + k * 32);
        g1vr[k][0] = *(const bf16x8*)(w1v0 + 128 * DIN + k * 32);
        g1vr[k][1] = *(const bf16x8*)(w1v1 + 128 * DIN + k * 32);
      }
    }

    // preload GEMM2 B (k2=0,1): hidden behind moments math
    const ushort_t* w2m0 = W2mu + (size_t)nrow0 * NRF + c * 128 + qoff;
    const ushort_t* w2m1 = W2mu + (size_t)nrow1 * NRF + c * 128 + qoff;
    const ushort_t* w2b0 = W2b + (size_t)nrow0 * NRF + c * 128 + qoff;
    const ushort_t* w2b1 = W2b + (size_t)nrow1 * NRF + c * 128 + qoff;
    const ushort_t* w2v0 = W2var + (size_t)nrow0 * NRF + c * 128 + qoff;
    const ushort_t* w2v1 = W2var + (size_t)nrow1 * NRF + c * 128 + qoff;
    bf16x8 g2m[2][2], g2b[2][2], g2v[2][2];
#pragma unroll
    for (int k2 = 0; k2 < 2; ++k2) {
      g2m[k2][0] = *(const bf16x8*)(w2m0 + k2 * 32);
      g2m[k2][1] = *(const bf16x8*)(w2m1 + k2 * 32);
      g2b[k2][0] = *(const bf16x8*)(w2b0 + k2 * 32);
      g2b[k2][1] = *(const bf16x8*)(w2b1 + k2 * 32);
      g2v[k2][0] = *(const bf16x8*)(w2v0 + k2 * 32);
      g2v[k2][1] = *(const bf16x8*)(w2v1 + k2 * 32);
    }

    // Barrier A: GEMM2(c-1) reads of Tm/Tv must complete before overwrite.
    __syncthreads();

    // ---- ReLU moments -> Tm/Tv (C-layout -> A-layout) ----
#pragma unroll
    for (int mt = 0; mt < 4; ++mt)
#pragma unroll
      for (int nt = 0; nt < 2; ++nt) {
        int col = (wave * 2 + nt) * 16 + l16;
#pragma unroll
        for (int r = 0; r < 4; ++r) {
          float mo, vo;
          relu_moments(am[mt][nt][r], av[mt][nt][r], mo, vo);
          int o = (mt * 16 + quad * 4 + r) * TLD + col;
          Tm[o] = f2bf(mo); Tv[o] = f2bf(vo);
        }
      }
    // Barrier B: writes visible before reads.
    __syncthreads();

    // ---- layer 2 with 2-deep B pipeline ----
#pragma unroll
    for (int k2 = 0; k2 < 4; ++k2) {
      const int cur2 = k2 & 1;
      bf16x8 c2m0 = g2m[cur2][0], c2m1 = g2m[cur2][1];
      bf16x8 c2b0 = g2b[cur2][0], c2b1 = g2b[cur2][1];
      bf16x8 c2v0 = g2v[cur2][0], c2v1 = g2v[cur2][1];
      if (k2 < 2) {
        g2m[k2][0] = *(const bf16x8*)(w2m0 + (k2 + 2) * 32);
        g2m[k2][1] = *(const bf16x8*)(w2m1 + (k2 + 2) * 32);
        g2b[k2][0] = *(const bf16x8*)(w2b0 + (k2 + 2) * 32);
        g2b[k2][1] = *(const bf16x8*)(w2b1 + (k2 + 2) * 32);
        g2v[k2][0] = *(const bf16x8*)(w2v0 + (k2 + 2) * 32);
        g2v[k2][1] = *(const bf16x8*)(w2v1 + (k2 + 2) * 32);
      }
#pragma unroll
      for (int mt = 0; mt < 4; ++mt) {
        int aoff = (mt * 16 + l16) * TLD + k2 * 32 + qoff;
        bf16x8 fam = *(const bf16x8*)(Tm + aoff);
        bf16x8 fav = *(const bf16x8*)(Tv + aoff);
        bf16x8 fsq = sq_frag(fam);
        acc_mo[mt][0] = __builtin_amdgcn_mfma_f32_16x16x32_bf16(fam, c2m0, acc_mo[mt][0], 0, 0, 0);
        acc_mo[mt][1] = __builtin_amdgcn_mfma_f32_16x16x32_bf16(fam, c2m1, acc_mo[mt][1], 0, 0, 0);
        acc_vo[mt][0] = __builtin_amdgcn_mfma_f32_16x16x32_bf16(fav, c2b0, acc_vo[mt][0], 0, 0, 0);
        acc_vo[mt][1] = __builtin_amdgcn_mfma_f32_16x16x32_bf16(fav, c2b1, acc_vo[mt][1], 0, 0, 0);
        acc_vo[mt][0] = __builtin_amdgcn_mfma_f32_16x16x32_bf16(fsq, c2v0, acc_vo[mt][0], 0, 0, 0);
        acc_vo[mt][1] = __builtin_amdgcn_mfma_f32_16x16x32_bf16(fsq, c2v1, acc_vo[mt][1], 0, 0, 0);
      }
    }
  }

  // ---- epilogue: precision-weighted scatter ----
#pragma unroll
  for (int mt = 0; mt < 4; ++mt)
#pragma unroll
    for (int j = 0; j < 2; ++j) {
      int dim = (wave * 2 + j) * 16 + l16;
#pragma unroll
      for (int r = 0; r < 4; ++r) {
        int prow = mt * 16 + quad * 4 + r;
        float mo = acc_mo[mt][j][r];
        float vo = acc_vo[mt][j][r];
        float prec = fast_rcp(vo);
        size_t o = (size_t)sidx[prow] * DOUT + dim;
        unsafeAtomicAdd(acc_means + o, prec * mo);
        unsafeAtomicAdd(acc_vars + o, prec);
      }
    }
}

// ---------------- kernel 2-fallback: R5 LDS-staged version --------------------
__global__ __launch_bounds__(256, 2) void fused_fb(
    const float* __restrict__ X,
    const unsigned* __restrict__ Xidx_raw,
    const ushort_t* __restrict__ W1mu, const ushort_t* __restrict__ W1var,
    const ushort_t* __restrict__ W2mu, const ushort_t* __restrict__ W2b,
    const ushort_t* __restrict__ W2var,
    const int* __restrict__ flag64,
    float* __restrict__ acc_means, float* __restrict__ acc_vars) {
  __shared__ ushort_t Xb[MT * XLD];
  __shared__ ushort_t Tm[MT * TLD];
  __shared__ ushort_t Tv[MT * TLD];
  __shared__ int sidx[MT];

  const int tid = threadIdx.x;
  const int p0  = blockIdx.x * MT;
  const int is64 = *flag64;

  if (tid < MT) {
    int p = p0 + tid;
    sidx[tid] = (int)(is64 ? Xidx_raw[2 * (size_t)p] : Xidx_raw[p]);
  }
#pragma unroll
  for (int i = 0; i < 16; ++i) {
    int idx4 = i * 256 + tid;
    int row  = idx4 >> 6;
    int c4   = idx4 & 63;
    f32x4v xv = *(const f32x4v*)(X + (size_t)(p0 + row) * DIN + c4 * 4);
    int off = row * XLD + c4 * 4;
    ushort4 b;
    b.x = f2bf(xv[0]); b.y = f2bf(xv[1]); b.z = f2bf(xv[2]); b.w = f2bf(xv[3]);
    *(ushort4*)(Xb + off) = b;
  }
  __syncthreads();

  const int lane = tid & 63;
  const int wave = tid >> 6;
  const int l16  = lane & 15;
  const int quad = lane >> 4;
  const int qoff = quad * 8;
  const int nrow0 = (wave * 2 + 0) * 16 + l16;
  const int nrow1 = (wave * 2 + 1) * 16 + l16;

  f32x4 acc_mo[4][2], acc_vo[4][2];
#pragma unroll
  for (int mt = 0; mt < 4; ++mt)
#pragma unroll
    for (int j = 0; j < 2; ++j) {
      acc_mo[mt][j] = (f32x4){0.f, 0.f, 0.f, 0.f};
      acc_vo[mt][j] = (f32x4){0.f, 0.f, 0.f, 0.f};
    }

  bf16x8 g1mu[2][2], g1vr[2][2];
#pragma unroll
  for (int k = 0; k < 2; ++k) {
    size_t o0 = (size_t)nrow0 * DIN + k * 32 + qoff;
    size_t o1 = (size_t)nrow1 * DIN + k * 32 + qoff;
    g1mu[k][0] = *(const bf16x8*)(W1mu + o0);
    g1mu[k][1] = *(const bf16x8*)(W1mu + o1);
    g1vr[k][0] = *(const bf16x8*)(W1var + o0);
    g1vr[k][1] = *(const bf16x8*)(W1var + o1);
  }

#pragma unroll 1
  for (int c = 0; c < 8; ++c) {
    f32x4 am[4][2], av[4][2];
#pragma unroll
    for (int mt = 0; mt < 4; ++mt)
#pragma unroll
      for (int nt = 0; nt < 2; ++nt) {
        am[mt][nt] = (f32x4){0.f, 0.f, 0.f, 0.f};
        av[mt][nt] = (f32x4){0.f, 0.f, 0.f, 0.f};
      }
    const size_t cbase1 = (size_t)(c * 128) * DIN;
#pragma unroll
    for (int k = 0; k < 8; ++k) {
      bf16x8 cmu0 = g1mu[k & 1][0], cmu1 = g1mu[k & 1][1];
      bf16x8 cvr0 = g1vr[k & 1][0], cvr1 = g1vr[k & 1][1];
      if (k < 6) {
        size_t o0 = cbase1 + (size_t)nrow0 * DIN + (k + 2) * 32 + qoff;
        size_t o1 = cbase1 + (size_t)nrow1 * DIN + (k + 2) * 32 + qoff;
        g1mu[k & 1][0] = *(const bf16x8*)(W1mu + o0);
        g1mu[k & 1][1] = *(const bf16x8*)(W1mu + o1);
        g1vr[k & 1][0] = *(const bf16x8*)(W1var + o0);
        g1vr[k & 1][1] = *(const bf16x8*)(W1var + o1);
      }
#pragma unroll
      for (int mt = 0; mt < 4; ++mt) {
        bf16x8 ax = *(const bf16x8*)(Xb + (mt * 16 + l16) * XLD + k * 32 + qoff);
        bf16x8 aq = sq_frag(ax);
        am[mt][0] = __builtin_amdgcn_mfma_f32_16x16x32_bf16(ax, cmu0, am[mt][0], 0, 0, 0);
        am[mt][1] = __builtin_amdgcn_mfma_f32_16x16x32_bf16(ax, cmu1, am[mt][1], 0, 0, 0);
        av[mt][0] = __builtin_amdgcn_mfma_f32_16x16x32_bf16(aq, cvr0, av[mt][0], 0, 0, 0);
        av[mt][1] = __builtin_amdgcn_mfma_f32_16x16x32_bf16(aq, cvr1, av[mt][1], 0, 0, 0);
      }
    }
    if (c < 7) {
      const size_t nbase1 = (size_t)((c + 1) * 128) * DIN;
#pragma unroll
      for (int k = 0; k < 2; ++k) {
        size_t o0 = nbase1 + (size_t)nrow0 * DIN + k * 32 + qoff;
        size_t o1 = nbase1 + (size_t)nrow1 * DIN + k * 32 + qoff;
        g1mu[k][0] = *(const bf16x8*)(W1mu + o0);
        g1mu[k][1] = *(const bf16x8*)(W1mu + o1);
        g1vr[k][0] = *(const bf16x8*)(W1var + o0);
        g1vr[k][1] = *(const bf16x8*)(W1var + o1);
      }
    }
    bf16x8 g2m[2][2], g2b[2][2], g2v[2][2];
    const size_t cbase2 = (size_t)(c * 128);
#pragma unroll
    for (int k2 = 0; k2 < 2; ++k2) {
      size_t o0 = (size_t)nrow0 * NRF + cbase2 + k2 * 32 + qoff;
      size_t o1 = (size_t)nrow1 * NRF + cbase2 + k2 * 32 + qoff;
      g2m[k2][0] = *(const bf16x8*)(W2mu + o0);
      g2m[k2][1] = *(const bf16x8*)(W2mu + o1);
      g2b[k2][0] = *(const bf16x8*)(W2b + o0);
      g2b[k2][1] = *(const bf16x8*)(W2b + o1);
      g2v[k2][0] = *(const bf16x8*)(W2var + o0);
      g2v[k2][1] = *(const bf16x8*)(W2var + o1);
    }
    __syncthreads();
#pragma unroll
    for (int mt = 0; mt < 4; ++mt)
#pragma unroll
      for (int nt = 0; nt < 2; ++nt) {
        int col = (wave * 2 + nt) * 16 + l16;
#pragma unroll
        for (int r = 0; r < 4; ++r) {
          float mo, vo;
          relu_moments(am[mt][nt][r], av[mt][nt][r], mo, vo);
          int o = (mt * 16 + quad * 4 + r) * TLD + col;
          Tm[o] = f2bf(mo); Tv[o] = f2bf(vo);
        }
      }
    __syncthreads();
#pragma unroll
    for (int k2 = 0; k2 < 4; ++k2) {
      bf16x8 c2m0 = g2m[k2 & 1][0], c2m1 = g2m[k2 & 1][1];
      bf16x8 c2b0 = g2b[k2 & 1][0], c2b1 = g2b[k2 & 1][1];
      bf16x8 c2v0 = g2v[k2 & 1][0], c2v1 = g2v[k2 & 1][1];
      if (k2 < 2) {
        size_t o0 = (size_t)nrow0 * NRF + cbase2 + (k2 + 2) * 32 + qoff;
        size_t o1 = (size_t)nrow1 * NRF + cbase2 + (k2 + 2) * 32 + qoff;
        g2m[k2][0] = *(const bf16x8*)(W2mu + o0);
        g2m[k2][1] = *(const bf16x8*)(W2mu + o1);
        g2b[k2][0] = *(const bf16x8*)(W2b + o0);
        g2b[k2][1] = *(const bf16x8*)(W2b + o1);
        g2v[k2][0] = *(const bf16x8*)(W2var + o0);
        g2v[k2][1] = *(const bf16x8*)(W2var + o1);
      }
#pragma unroll
      for (int mt = 0; mt < 4; ++mt) {
        int aoff = (mt * 16 + l16) * TLD + k2 * 32 + qoff;
        bf16x8 fam = *(const bf16x8*)(Tm + aoff);
        bf16x8 fav = *(const bf16x8*)(Tv + aoff);
        bf16x8 fsq = sq_frag(fam);
        acc_mo[mt][0] = __builtin_amdgcn_mfma_f32_16x16x32_bf16(fam, c2m0, acc_mo[mt][0], 0, 0, 0);
        acc_mo[mt][1] = __builtin_amdgcn_mfma_f32_16x16x32_bf16(fam, c2m1, acc_mo[mt][1], 0, 0, 0);
        acc_vo[mt][0] = __builtin_amdgcn_mfma_f32_16x16x32_bf16(fav, c2b0, acc_vo[mt][0], 0, 0, 0);
        acc_vo[mt][1] = __builtin_amdgcn_mfma_f32_16x16x32_bf16(fav, c2b1, acc_vo[mt][1], 0, 0, 0);
        acc_vo[mt][0] = __builtin_amdgcn_mfma_f32_16x16x32_bf16(fsq, c2v0, acc_vo[mt][0], 0, 0, 0);
        acc_vo[mt][1] = __builtin_amdgcn_mfma_f32_16x16x32_bf16(fsq, c2v1, acc_vo[mt][1], 0, 0, 0);
      }
    }
  }
#pragma unroll
  for (int mt = 0; mt < 4; ++mt)
#pragma unroll
    for (int j = 0; j < 2; ++j) {
      int dim = (wave * 2 + j) * 16 + l16;
#pragma unroll
      for (int r = 0; r < 4; ++r) {
        int prow = mt * 16 + quad * 4 + r;
        float mo = acc_mo[mt][j][r];
        float vo = acc_vo[mt][j][r];
        float prec = fast_rcp(vo);
        size_t o = (size_t)sidx[prow] * DOUT + dim;
        unsafeAtomicAdd(acc_means + o, prec * mo);
        unsafeAtomicAdd(acc_vars + o, prec);
      }
    }
}

// ---------------- kernel 3: finalize ------------------------------------------
__global__ __launch_bounds__(256) void finalize_kernel(float* __restrict__ means,
                                                       float* __restrict__ vars) {
  int i = blockIdx.x * 256 + threadIdx.x;   // covers S*DOUT exactly
  float p  = vars[i];
  float pm = means[i];
  float var = 1.0f / p;
  means[i] = pm * var;
  vars[i]  = var;
}

extern "C" void kernel_launch(void* const* d_in, const int* in_sizes, int n_in,
                              void* d_out, int out_size, void* d_ws, size_t ws_size,
                              hipStream_t stream) {
  const float*    X     = (const float*)d_in[0];
  const unsigned* Xidx  = (const unsigned*)d_in[1];
  const float*    W1mu  = (const float*)d_in[2];
  const float*    W1var = (const float*)d_in[3];
  const float*    W2mu  = (const float*)d_in[4];
  const float*    W2var = (const float*)d_in[5];
  float* out = (float*)d_out;

  ushort_t* w1mu_bf  = (ushort_t*)d_ws;
  ushort_t* w1var_bf = w1mu_bf + NRF * DIN;       // 262144
  ushort_t* w2mu_bf  = w1var_bf + NRF * DIN;
  ushort_t* w2b_bf   = w2mu_bf + NRF * DOUT;      // 131072
  ushort_t* w2var_bf = w2b_bf + NRF * DOUT;
  int* flag = (int*)(w2var_bf + NRF * DOUT);

  // X bf16 arrays at a 2 MB offset (past weights), 67.1 MB each
  const size_t xoff_bytes = 2u << 20;
  const size_t xelems = (size_t)NPTS * DIN;                // 33554432
  ushort_t* xbf = (ushort_t*)((char*)d_ws + xoff_bytes);
  ushort_t* xsq = xbf + xelems;
  const size_t need = xoff_bytes + 2 * xelems * sizeof(ushort_t);

  hipMemsetAsync(d_out, 0, (size_t)out_size * sizeof(float), stream);
  detect_idx_kernel<<<1, 256, 0, stream>>>(Xidx, flag);
  convert_kernel<<<(NRF * DIN) / 256, 256, 0, stream>>>(
      W1mu, W1var, W2mu, W2var, w1mu_bf, w1var_bf, w2mu_bf, w2b_bf, w2var_bf);

  if (ws_size >= need) {
    xprep_kernel<<<(int)(xelems / 4 / 256), 256, 0, stream>>>(X, xbf, xsq);
    fused_gx<<<NWG, 256, 0, stream>>>(
        xbf, xsq, Xidx, w1mu_bf, w1var_bf, w2mu_bf, w2b_bf, w2var_bf, flag,
        out, out + (size_t)SGRP * DOUT);
  } else {
    fused_fb<<<NWG, 256, 0, stream>>>(
        X, Xidx, w1mu_bf, w1var_bf, w2mu_bf, w2b_bf, w2var_bf, flag,
        out, out + (size_t)SGRP * DOUT);
  }
  finalize_kernel<<<(SGRP * DOUT) / 256, 256, 0, stream>>>(
      out, out + (size_t)SGRP * DOUT);
}

// Round 8
// 653.884 us; speedup vs baseline: 3.0279x; 3.0279x over previous
//
#include <hip/hip_runtime.h>

// DGP-RF embeddings, fused MFMA. Round 8 (R7 fixed: cvt_pk_fp8 'hi' must be
// an immediate -> template parameter).
// Thesis: R5 (615us) is VALU-bound (54% busy) with MFMA-busy near its floor.
// Biggest removable VALU block: all sq_frag squaring (x^2 recomputed 8x/chunk
// in GEMM1, m'^2 per k2 in GEMM2). Fix: move the VARIANCE path to fp8 e4m3
// (HW MFMA rate = bf16 rate):
//   - staging converts x^2 -> fp8 LDS table ONCE (Xq8)
//   - W1var, W2b=(W2mu^2+W2var), W2var pre-scaled x256 into fp8, descale
//     2^-8 folded into moments input / epilogue
//   - moments write Tv, T3=m'^2 as fp8 tables; GEMM2 var-MFMAs are fp8
//   - mean path stays bf16 end-to-end
// T-tables are 64-wide chunks (16 chunks) -> LDS 69.4KB, 2 blk/CU.
// R6 lesson: X staged in LDS once (global per-k A-gathers = 3TB/s HBM).

#define NPTS   131072
#define SGRP   16384
#define DIN    256
#define NRF    1024
#define DOUT   128
#define MT     64            // points per WG
#define NWG    (NPTS / MT)   // 2048

#define XLD    264   // bf16 X row stride
#define XQLD   264   // fp8 x^2 row stride
#define TMLD   72    // bf16 m' row stride
#define TVLD   72    // fp8 v'/m'^2 row stride

typedef unsigned short ushort_t;
typedef unsigned char  uchar_t;
typedef __attribute__((ext_vector_type(8))) short bf16x8;
typedef __attribute__((ext_vector_type(4))) float f32x4;
typedef __attribute__((ext_vector_type(4))) float f32x4v;

__device__ __forceinline__ unsigned short f2bf(float f) {
  unsigned u = __float_as_uint(f);
  u += 0x7fffu + ((u >> 16) & 1u);   // round-to-nearest-even
  return (unsigned short)(u >> 16);
}

// pack 2 floats -> 2 fp8 e4m3 bytes into (HI? bytes 2,3 : bytes 0,1) of old
template <bool HI>
__device__ __forceinline__ unsigned cvt2_fp8(float a, float b, unsigned old) {
#if __has_builtin(__builtin_amdgcn_cvt_pk_fp8_f32)
  return __builtin_amdgcn_cvt_pk_fp8_f32(a, b, old, HI);
#else
  auto enc = [](float x) -> unsigned {
    if (!(x > 0.00097656f)) return 0u;
    if (x >= 448.f) return 0x7Eu;
    union { float f; unsigned u; } v; v.f = x;
    int e = (int)(v.u >> 23) - 127;
    if (e < -6) { int n = (int)(x * 512.f + 0.5f); return (unsigned)n; }
    v.u += 0x0007FFFFu + ((v.u >> 20) & 1u);
    e = (int)(v.u >> 23) - 127;
    if (e > 8) return 0x7Eu;
    return (unsigned)(((e + 7) << 3) | ((v.u >> 20) & 7u));
  };
  unsigned p = (enc(a) | (enc(b) << 8));
  return HI ? ((old & 0x0000ffffu) | (p << 16)) : ((old & 0xffff0000u) | p);
#endif
}

__device__ __forceinline__ float fast_rcp(float x) {
#if __has_builtin(__builtin_amdgcn_rcpf)
  return __builtin_amdgcn_rcpf(x);
#else
  return 1.0f / x;
#endif
}
__device__ __forceinline__ float fast_rsq(float x) {
#if __has_builtin(__builtin_amdgcn_rsqf)
  return __builtin_amdgcn_rsqf(x);
#else
  return rsqrtf(x);
#endif
}
__device__ __forceinline__ float fast_exp2(float x) {
#if __has_builtin(__builtin_amdgcn_exp2f)
  return __builtin_amdgcn_exp2f(x);
#else
  return exp2f(x);
#endif
}

// Exact Gaussian-ReLU moments (A&S 7.1.26 erf, one shared exp2).
__device__ __forceinline__ void relu_moments(float mu, float v,
                                             float& mo, float& vo) {
  float vpe = v + 1e-8f;
  float rsq = fast_rsq(vpe);
  float s   = vpe * rsq;
  float z   = mu * rsq;
  float E   = fast_exp2(-0.7213475204444817f * z * z);  // exp(-z^2/2)
  float x   = 0.70710678118654752f * fabsf(z);
  float t   = fast_rcp(fmaf(0.3275911f, x, 1.0f));
  float poly = t * fmaf(t, fmaf(t, fmaf(t, fmaf(t, 1.061405429f, -1.453152027f),
                                        1.421413741f), -0.284496736f), 0.254829592f);
  float q   = 0.5f * poly * E;
  float Phi = (z >= 0.0f) ? (1.0f - q) : q;
  float phi = 0.3989422804014327f * E;
  float sphi = s * phi;
  mo = fmaf(mu, Phi, sphi);
  float ey2 = fmaf(fmaf(mu, mu, v), Phi, mu * sphi);
  vo = fmaxf(fmaf(-mo, mo, ey2), 1e-6f);
}

// ---------------- kernel 0: detect whether X_idx is int32 or int64 -------------
__global__ void detect_idx_kernel(const unsigned* __restrict__ raw,
                                  int* __restrict__ flag) {
  __shared__ int any_nz;
  if (threadIdx.x == 0) any_nz = 0;
  __syncthreads();
  if (raw[2 * threadIdx.x + 1] != 0u) atomicOr(&any_nz, 1);
  __syncthreads();
  if (threadIdx.x == 0) *flag = (any_nz == 0) ? 1 : 0;   // 1 => int64
}

// ---------------- kernel 1: convert weights (bf16 mean path, fp8 var path) ----
__global__ __launch_bounds__(256) void convert_kernel(
    const float* __restrict__ W1mu, const float* __restrict__ W1var,
    const float* __restrict__ W2mu, const float* __restrict__ W2var,
    ushort_t* __restrict__ w1mu_bf, uchar_t* __restrict__ w1var8,
    ushort_t* __restrict__ w2mu_bf, uchar_t* __restrict__ w2b8,
    uchar_t* __restrict__ w2var8) {
  int i4 = (blockIdx.x * 256 + threadIdx.x) * 4;   // grid covers 262144
  {
    f32x4v m = *(const f32x4v*)(W1mu + i4);
    ushort4 b; b.x = f2bf(m[0]); b.y = f2bf(m[1]); b.z = f2bf(m[2]); b.w = f2bf(m[3]);
    *(ushort4*)(w1mu_bf + i4) = b;
    f32x4v v = *(const f32x4v*)(W1var + i4);
    unsigned p = cvt2_fp8<false>(v[0] * 256.f, v[1] * 256.f, 0u);
    p = cvt2_fp8<true>(v[2] * 256.f, v[3] * 256.f, p);
    *(unsigned*)(w1var8 + i4) = p;
  }
  if (i4 < NRF * DOUT) {
    f32x4v m = *(const f32x4v*)(W2mu + i4);
    f32x4v v = *(const f32x4v*)(W2var + i4);
    ushort4 b; b.x = f2bf(m[0]); b.y = f2bf(m[1]); b.z = f2bf(m[2]); b.w = f2bf(m[3]);
    *(ushort4*)(w2mu_bf + i4) = b;
    unsigned pb = cvt2_fp8<false>(fmaf(m[0], m[0], v[0]) * 256.f,
                                  fmaf(m[1], m[1], v[1]) * 256.f, 0u);
    pb = cvt2_fp8<true>(fmaf(m[2], m[2], v[2]) * 256.f,
                        fmaf(m[3], m[3], v[3]) * 256.f, pb);
    *(unsigned*)(w2b8 + i4) = pb;
    unsigned pv = cvt2_fp8<false>(v[0] * 256.f, v[1] * 256.f, 0u);
    pv = cvt2_fp8<true>(v[2] * 256.f, v[3] * 256.f, pv);
    *(unsigned*)(w2var8 + i4) = pv;
  }
}

// ---------------- kernel 2: fused DGP-RF block --------------------------------
__global__ __launch_bounds__(256, 2) void fused_kernel(
    const float* __restrict__ X,
    const unsigned* __restrict__ Xidx_raw,
    const ushort_t* __restrict__ W1mu, const uchar_t* __restrict__ W1var8,
    const ushort_t* __restrict__ W2mu, const uchar_t* __restrict__ W2b8,
    const uchar_t* __restrict__ W2var8,
    const int* __restrict__ flag64,
    float* __restrict__ acc_means, float* __restrict__ acc_vars) {
  __shared__ ushort_t Xb[MT * XLD];    // 33.8 KB bf16 x
  __shared__ uchar_t  Xq8[MT * XQLD];  // 16.9 KB fp8 x^2
  __shared__ ushort_t Tm[MT * TMLD];   //  9.2 KB bf16 m'
  __shared__ uchar_t  Tv8[MT * TVLD];  //  4.6 KB fp8 v'
  __shared__ uchar_t  T38[MT * TVLD];  //  4.6 KB fp8 m'^2
  __shared__ int sidx[MT];

  const int tid = threadIdx.x;
  const int p0  = blockIdx.x * MT;
  const int is64 = *flag64;

  if (tid < MT) {
    int p = p0 + tid;
    sidx[tid] = (int)(is64 ? Xidx_raw[2 * (size_t)p] : Xidx_raw[p]);
  }
  // stage X tile: bf16 x and fp8 x^2, converted once here
#pragma unroll
  for (int i = 0; i < 16; ++i) {
    int idx4 = i * 256 + tid;       // 0..4095 (64 rows x 64 float4)
    int row  = idx4 >> 6;
    int c4   = idx4 & 63;
    f32x4v xv = *(const f32x4v*)(X + (size_t)(p0 + row) * DIN + c4 * 4);
    ushort4 b;
    b.x = f2bf(xv[0]); b.y = f2bf(xv[1]); b.z = f2bf(xv[2]); b.w = f2bf(xv[3]);
    *(ushort4*)(Xb + row * XLD + c4 * 4) = b;
    unsigned q = cvt2_fp8<false>(xv[0] * xv[0], xv[1] * xv[1], 0u);
    q = cvt2_fp8<true>(xv[2] * xv[2], xv[3] * xv[3], q);
    *(unsigned*)(Xq8 + row * XQLD + c4 * 4) = q;
  }
  __syncthreads();

  const int lane = tid & 63;
  const int wave = tid >> 6;
  const int l16  = lane & 15;
  const int quad = lane >> 4;
  const int qoff = quad * 8;

  const int nrow0 = (wave * 2 + 0) * 16 + l16;   // GEMM2 B rows (dout)
  const int nrow1 = (wave * 2 + 1) * 16 + l16;

  f32x4 acc_mo[4][2], acc_vo[4][2];
#pragma unroll
  for (int mt = 0; mt < 4; ++mt)
#pragma unroll
    for (int j = 0; j < 2; ++j) {
      acc_mo[mt][j] = (f32x4){0.f, 0.f, 0.f, 0.f};
      acc_vo[mt][j] = (f32x4){0.f, 0.f, 0.f, 0.f};
    }

#pragma unroll 1
  for (int c = 0; c < 16; ++c) {   // 16 chunks x 64 RFs
    // ---- GEMM1: this wave owns RF rows c*64 + wave*16 + l16 ----
    const ushort_t* w1m = W1mu  + (size_t)(c * 64 + wave * 16 + l16) * DIN + qoff;
    const uchar_t*  w1v = W1var8 + (size_t)(c * 64 + wave * 16 + l16) * DIN + qoff;
    bf16x8 bmu[8]; long long bvr[8];
#pragma unroll
    for (int k = 0; k < 8; ++k) {
      bmu[k] = *(const bf16x8*)(w1m + k * 32);
      bvr[k] = *(const long long*)(w1v + k * 32);
    }
    f32x4 am[4], av[4];
#pragma unroll
    for (int mt = 0; mt < 4; ++mt) {
      am[mt] = (f32x4){0.f, 0.f, 0.f, 0.f};
      av[mt] = (f32x4){0.f, 0.f, 0.f, 0.f};
    }
#pragma unroll
    for (int k = 0; k < 8; ++k) {
#pragma unroll
      for (int mt = 0; mt < 4; ++mt) {
        bf16x8 ax = *(const bf16x8*)(Xb + (mt * 16 + l16) * XLD + k * 32 + qoff);
        long long aq = *(const long long*)(Xq8 + (mt * 16 + l16) * XQLD + k * 32 + qoff);
        am[mt] = __builtin_amdgcn_mfma_f32_16x16x32_bf16(ax, bmu[k], am[mt], 0, 0, 0);
        av[mt] = __builtin_amdgcn_mfma_f32_16x16x32_fp8_fp8(aq, bvr[k], av[mt], 0, 0, 0);
      }
    }

    // ---- preload GEMM2 B (independent of LDS; overlaps moments) ----
    const ushort_t* w2m0 = W2mu + (size_t)nrow0 * NRF + c * 64 + qoff;
    const ushort_t* w2m1 = W2mu + (size_t)nrow1 * NRF + c * 64 + qoff;
    const uchar_t* w2b0 = W2b8 + (size_t)nrow0 * NRF + c * 64 + qoff;
    const uchar_t* w2b1 = W2b8 + (size_t)nrow1 * NRF + c * 64 + qoff;
    const uchar_t* w2v0 = W2var8 + (size_t)nrow0 * NRF + c * 64 + qoff;
    const uchar_t* w2v1 = W2var8 + (size_t)nrow1 * NRF + c * 64 + qoff;
    bf16x8 b2m[2][2]; long long b2b[2][2], b2v[2][2];
#pragma unroll
    for (int k2 = 0; k2 < 2; ++k2) {
      b2m[0][k2] = *(const bf16x8*)(w2m0 + k2 * 32);
      b2m[1][k2] = *(const bf16x8*)(w2m1 + k2 * 32);
      b2b[0][k2] = *(const long long*)(w2b0 + k2 * 32);
      b2b[1][k2] = *(const long long*)(w2b1 + k2 * 32);
      b2v[0][k2] = *(const long long*)(w2v0 + k2 * 32);
      b2v[1][k2] = *(const long long*)(w2v1 + k2 * 32);
    }

    // Barrier A: prior chunk's GEMM2 T-reads complete before overwrite.
    __syncthreads();

    // ---- ReLU moments -> Tm (bf16), Tv8 (fp8 v'), T38 (fp8 m'^2) ----
    const int col = wave * 16 + l16;   // chunk-local column
#pragma unroll
    for (int mt = 0; mt < 4; ++mt) {
#pragma unroll
      for (int r = 0; r < 4; ++r) {
        float mo, vo;
        relu_moments(am[mt][r], av[mt][r] * 0.00390625f, mo, vo);
        int row = mt * 16 + quad * 4 + r;
        Tm[row * TMLD + col] = f2bf(mo);
        Tv8[row * TVLD + col] = (uchar_t)(cvt2_fp8<false>(vo, vo, 0u) & 0xffu);
        T38[row * TVLD + col] = (uchar_t)(cvt2_fp8<false>(mo * mo, mo * mo, 0u) & 0xffu);
      }
    }
    // Barrier B: T writes visible.
    __syncthreads();

    // ---- GEMM2 over this 64-RF chunk (2 K-steps) ----
#pragma unroll
    for (int k2 = 0; k2 < 2; ++k2) {
#pragma unroll
      for (int mt = 0; mt < 4; ++mt) {
        int ar = mt * 16 + l16;
        bf16x8 fam = *(const bf16x8*)(Tm + ar * TMLD + k2 * 32 + qoff);
        long long fav = *(const long long*)(Tv8 + ar * TVLD + k2 * 32 + qoff);
        long long f3  = *(const long long*)(T38 + ar * TVLD + k2 * 32 + qoff);
        acc_mo[mt][0] = __builtin_amdgcn_mfma_f32_16x16x32_bf16(fam, b2m[0][k2], acc_mo[mt][0], 0, 0, 0);
        acc_mo[mt][1] = __builtin_amdgcn_mfma_f32_16x16x32_bf16(fam, b2m[1][k2], acc_mo[mt][1], 0, 0, 0);
        acc_vo[mt][0] = __builtin_amdgcn_mfma_f32_16x16x32_fp8_fp8(fav, b2b[0][k2], acc_vo[mt][0], 0, 0, 0);
        acc_vo[mt][1] = __builtin_amdgcn_mfma_f32_16x16x32_fp8_fp8(fav, b2b[1][k2], acc_vo[mt][1], 0, 0, 0);
        acc_vo[mt][0] = __builtin_amdgcn_mfma_f32_16x16x32_fp8_fp8(f3, b2v[0][k2], acc_vo[mt][0], 0, 0, 0);
        acc_vo[mt][1] = __builtin_amdgcn_mfma_f32_16x16x32_fp8_fp8(f3, b2v[1][k2], acc_vo[mt][1], 0, 0, 0);
      }
    }
  }

  // ---- epilogue: precision-weighted scatter (acc_vo carries x256 scale) ----
#pragma unroll
  for (int mt = 0; mt < 4; ++mt)
#pragma unroll
    for (int j = 0; j < 2; ++j) {
      int dim = (wave * 2 + j) * 16 + l16;
#pragma unroll
      for (int r = 0; r < 4; ++r) {
        int prow = mt * 16 + quad * 4 + r;
        float mo = acc_mo[mt][j][r];
        float vo = fmaf(acc_vo[mt][j][r], 0.00390625f, 1e-6f);
        float prec = fast_rcp(vo);
        size_t o = (size_t)sidx[prow] * DOUT + dim;
        unsafeAtomicAdd(acc_means + o, prec * mo);
        unsafeAtomicAdd(acc_vars + o, prec);
      }
    }
}

// ---------------- kernel 3: finalize ------------------------------------------
__global__ __launch_bounds__(256) void finalize_kernel(float* __restrict__ means,
                                                       float* __restrict__ vars) {
  int i = blockIdx.x * 256 + threadIdx.x;   // covers S*DOUT exactly
  float p  = vars[i];
  float pm = means[i];
  float var = 1.0f / p;
  means[i] = pm * var;
  vars[i]  = var;
}

extern "C" void kernel_launch(void* const* d_in, const int* in_sizes, int n_in,
                              void* d_out, int out_size, void* d_ws, size_t ws_size,
                              hipStream_t stream) {
  const float*    X     = (const float*)d_in[0];
  const unsigned* Xidx  = (const unsigned*)d_in[1];
  const float*    W1mu  = (const float*)d_in[2];
  const float*    W1var = (const float*)d_in[3];
  const float*    W2mu  = (const float*)d_in[4];
  const float*    W2var = (const float*)d_in[5];
  float* out = (float*)d_out;

  ushort_t* w1mu_bf = (ushort_t*)d_ws;                    // 262144 u16
  uchar_t*  w1var8  = (uchar_t*)(w1mu_bf + NRF * DIN);    // 262144 u8
  ushort_t* w2mu_bf = (ushort_t*)(w1var8 + NRF * DIN);    // 131072 u16
  uchar_t*  w2b8    = (uchar_t*)(w2mu_bf + NRF * DOUT);   // 131072 u8
  uchar_t*  w2var8  = w2b8 + NRF * DOUT;                  // 131072 u8
  int* flag = (int*)(w2var8 + NRF * DOUT);

  (void)hipMemsetAsync(d_out, 0, (size_t)out_size * sizeof(float), stream);
  detect_idx_kernel<<<1, 256, 0, stream>>>(Xidx, flag);
  convert_kernel<<<(NRF * DIN) / 4 / 256, 256, 0, stream>>>(
      W1mu, W1var, W2mu, W2var, w1mu_bf, w1var8, w2mu_bf, w2b8, w2var8);
  fused_kernel<<<NWG, 256, 0, stream>>>(
      X, Xidx, w1mu_bf, w1var8, w2mu_bf, w2b8, w2var8, flag,
      out, out + (size_t)SGRP * DOUT);
  finalize_kernel<<<(SGRP * DOUT) / 256, 256, 0, stream>>>(
      out, out + (size_t)SGRP * DOUT);
}